// Round 11
// baseline (736.137 us; speedup 1.0000x reference)
//
#include <hip/hip_runtime.h>
#include <stdint.h>
#include <math.h>

#define NB 4
#define NN 1024
#define ND 64
#define RP 68   // padded f32 LDS row (multiple of 4 for b128 alignment)

// Static device scratch: f64 (exact fallback) + f32 (fast path) h arrays
__device__ double g_hs64[NB * NN * ND];
__device__ double g_hd64[NB * NN * ND];
__device__ float  g_hs32[NB * NN * ND];
__device__ float  g_hd32[NB * NN * ND];
__device__ double g_w2d[ND];
__device__ float  g_w2f[ND];

// ---- Threefry-2x32-20 core ----
__device__ __forceinline__ void threefry_core(uint32_t K0, uint32_t K1,
                                              uint32_t x0, uint32_t x1,
                                              uint32_t& o0, uint32_t& o1) {
  const uint32_t K2 = K0 ^ K1 ^ 0x1BD11BDAu;
  x0 += K0; x1 += K1;
#define TF_RND(r) { x0 += x1; x1 = (x1 << r) | (x1 >> (32 - r)); x1 ^= x0; }
  TF_RND(13) TF_RND(15) TF_RND(26) TF_RND(6)
  x0 += K1; x1 += K2 + 1u;
  TF_RND(17) TF_RND(29) TF_RND(16) TF_RND(24)
  x0 += K2; x1 += K0 + 2u;
  TF_RND(13) TF_RND(15) TF_RND(26) TF_RND(6)
  x0 += K0; x1 += K1 + 3u;
  TF_RND(17) TF_RND(29) TF_RND(16) TF_RND(24)
  x0 += K1; x1 += K2 + 4u;
  TF_RND(13) TF_RND(15) TF_RND(26) TF_RND(6)
  x0 += K2; x1 += K0 + 5u;
#undef TF_RND
  o0 = x0; o1 = x1;
}

// jax_threefry_partitionable stream (verified r3): word(L) = o0^o1, x=(0,L)
__device__ __forceinline__ uint32_t rand_word(uint32_t L) {
  uint32_t o0, o1;
  threefry_core(0u, 42u, 0u, L, o0, o1);
  return o0 ^ o1;
}

// exact f32 uniform(tiny,1) — bit-identical to JAX
__device__ __forceinline__ float u_from_word(uint32_t w) {
  uint32_t fb = (w >> 9) | 0x3f800000u;
  float f = __uint_as_float(fb) - 1.0f;
  const float tinyf = 1.17549435e-38f;
  return fmaxf(tinyf, f + tinyf);
}

// ---- exact-f64 fallback for near-boundary cells (matches r3/r4 pipeline) ----
__device__ __attribute__((noinline)) float decide_fallback(int b, int i, int j,
                                                           uint32_t m, double b2d) {
  const double* hsi = g_hs64 + ((size_t)(b * NN + i)) * ND;
  const double* hdi = g_hd64 + ((size_t)(b * NN + i)) * ND;
  const double* hsj = g_hs64 + ((size_t)(b * NN + j)) * ND;
  const double* hdj = g_hd64 + ((size_t)(b * NN + j)) * ND;
  double l1 = 0.0, l2 = 0.0;
  for (int d = 0; d < ND; ++d) {
    double w = g_w2d[d];
    l1 += fmax(hsi[d] + hdj[d], 0.0) * w;
    l2 += fmax(hsj[d] + hdi[d], 0.0) * w;
  }
  double sym = 0.5 * (l1 + l2) + b2d;
  double E = exp(sym);
  double L0 = -log((double)u_from_word(rand_word(2u * m)));
  double L1 = -log((double)u_from_word(rand_word(2u * m + 1u)));
  return (E * L1 >= L0) ? 1.0f : 0.0f;
}

// ---- Stage 1: 512 blocks, 4 rows/thread, 8 f64 chains (same FMA order) ----
__global__ __launch_bounds__(256) void stage1(const float* __restrict__ nf,
                                              const float* __restrict__ W1,
                                              const float* __restrict__ b1,
                                              const float* __restrict__ W2) {
  __shared__ float w1s[2 * ND][ND];   // 32 KB
  __shared__ float rows[8][ND];       // 2 KB
  const int tid = threadIdx.x;
  const float4* W14 = (const float4*)W1;
  float4* w1s4 = (float4*)w1s;
  #pragma unroll
  for (int p = 0; p < 8; ++p) w1s4[tid + 256 * p] = W14[tid + 256 * p];
  if (tid < 128) {     // 8 rows x 64 = 128 float4
    const int r = tid >> 4, c4 = (tid & 15) << 2;
    *(float4*)&rows[r][c4] =
        *(const float4*)(nf + ((size_t)blockIdx.x * 8 + r) * ND + c4);
  }
  __syncthreads();

  const int e = tid & 63;
  const int rg = tid >> 6;            // 0..3 -> rows rg*2, rg*2+1
  const int r0 = rg * 2, r1 = rg * 2 + 1;

  double as0 = 0.0, as1 = 0.0, ad0 = 0.0, ad1 = 0.0;
  #pragma unroll 4
  for (int k = 0; k < ND; ++k) {
    const double ws = (double)w1s[k][e];
    const double wd = (double)w1s[ND + k][e];
    const double x0 = (double)rows[r0][k];
    const double x1 = (double)rows[r1][k];
    as0 = fma(x0, ws, as0);  as1 = fma(x1, ws, as1);
    ad0 = fma(x0, wd, ad0);  ad1 = fma(x1, wd, ad1);
  }
  const double b1e = (double)b1[e];
  ad0 += b1e;  ad1 += b1e;

  const size_t bn0 = (size_t)blockIdx.x * 8 + r0;
  const size_t bn1 = bn0 + 1;
  g_hs64[bn0 * ND + e] = as0;  g_hs64[bn1 * ND + e] = as1;
  g_hd64[bn0 * ND + e] = ad0;  g_hd64[bn1 * ND + e] = ad1;
  g_hs32[bn0 * ND + e] = (float)as0;  g_hs32[bn1 * ND + e] = (float)as1;
  g_hd32[bn0 * ND + e] = (float)ad0;  g_hd32[bn1 * ND + e] = (float)ad1;

  if (blockIdx.x == 0 && tid < ND) {
    g_w2d[tid] = (double)W2[tid];
    g_w2f[tid] = W2[tid];
  }
}

// ---- Stage 2: f32 32x32 pair tile, ping-pong register pipeline ----
__global__ __launch_bounds__(256, 4) void stage2(const float* __restrict__ b2,
                                                 float* __restrict__ adj,
                                                 float* __restrict__ logits) {
  const int t = blockIdx.x;
  const int b = t / 528;
  const int k = t - b * 528;
#define TRI_S(x) ((x) * 32 - ((x) * ((x) - 1)) / 2)
  int bi = (int)((65.0 - sqrt((double)(4225 - 8 * k))) * 0.5);
  while (k >= TRI_S(bi + 1)) ++bi;
  while (k < TRI_S(bi)) --bi;
  const int bj = bi + (k - TRI_S(bi));
#undef TRI_S
  const int i0 = bi * 32, j0 = bj * 32;

  __shared__ float sh_si[32][RP], sh_di[32][RP];
  __shared__ float sh_sj[32][RP], sh_dj[32][RP];
  __shared__ float w2s[ND];

  const int tid = threadIdx.x;
  {
    const float4* src_si = (const float4*)(g_hs32 + ((size_t)(b * NN + i0)) * ND);
    const float4* src_di = (const float4*)(g_hd32 + ((size_t)(b * NN + i0)) * ND);
    const float4* src_sj = (const float4*)(g_hs32 + ((size_t)(b * NN + j0)) * ND);
    const float4* src_dj = (const float4*)(g_hd32 + ((size_t)(b * NN + j0)) * ND);
    #pragma unroll
    for (int p = 0; p < 2; ++p) {
      const int q = tid + 256 * p;          // float4 index, 0..511
      const int r = q >> 4, c4 = (q & 15) << 2;
      *(float4*)&sh_si[r][c4] = src_si[q];
      *(float4*)&sh_di[r][c4] = src_di[q];
      *(float4*)&sh_sj[r][c4] = src_sj[q];
      *(float4*)&sh_dj[r][c4] = src_dj[q];
    }
    if (tid < ND) w2s[tid] = g_w2f[tid];
  }
  __syncthreads();

  const int tx = tid & 15, ty = tid >> 4;

  float a1[2][2] = {{0.f, 0.f}, {0.f, 0.f}};
  float a2[2][2] = {{0.f, 0.f}, {0.f, 0.f}};

  // ping-pong register sets A/B: load group g+1 while computing group g
#define LOADG(W4, SI0, SI1, DI0, DI1, SJ0, SJ1, DJ0, DJ1, db)                 \
  W4  = *(const float4*)&w2s[db];                                             \
  SI0 = *(const float4*)&sh_si[ty][db];                                       \
  SI1 = *(const float4*)&sh_si[ty + 16][db];                                  \
  DI0 = *(const float4*)&sh_di[ty][db];                                       \
  DI1 = *(const float4*)&sh_di[ty + 16][db];                                  \
  SJ0 = *(const float4*)&sh_sj[tx][db];                                       \
  SJ1 = *(const float4*)&sh_sj[tx + 16][db];                                  \
  DJ0 = *(const float4*)&sh_dj[tx][db];                                       \
  DJ1 = *(const float4*)&sh_dj[tx + 16][db];

#define ACCX(W4, SI0, SI1, DI0, DI1, SJ0, SJ1, DJ0, DJ1, X)                   \
  {                                                                           \
    const float w = W4.X;                                                     \
    a1[0][0] = fmaf(fmaxf(SI0.X + DJ0.X, 0.f), w, a1[0][0]);                  \
    a1[0][1] = fmaf(fmaxf(SI0.X + DJ1.X, 0.f), w, a1[0][1]);                  \
    a1[1][0] = fmaf(fmaxf(SI1.X + DJ0.X, 0.f), w, a1[1][0]);                  \
    a1[1][1] = fmaf(fmaxf(SI1.X + DJ1.X, 0.f), w, a1[1][1]);                  \
    a2[0][0] = fmaf(fmaxf(SJ0.X + DI0.X, 0.f), w, a2[0][0]);                  \
    a2[0][1] = fmaf(fmaxf(SJ1.X + DI0.X, 0.f), w, a2[0][1]);                  \
    a2[1][0] = fmaf(fmaxf(SJ0.X + DI1.X, 0.f), w, a2[1][0]);                  \
    a2[1][1] = fmaf(fmaxf(SJ1.X + DI1.X, 0.f), w, a2[1][1]);                  \
  }

#define COMPG(W4, SI0, SI1, DI0, DI1, SJ0, SJ1, DJ0, DJ1)                     \
  ACCX(W4, SI0, SI1, DI0, DI1, SJ0, SJ1, DJ0, DJ1, x)                         \
  ACCX(W4, SI0, SI1, DI0, DI1, SJ0, SJ1, DJ0, DJ1, y)                         \
  ACCX(W4, SI0, SI1, DI0, DI1, SJ0, SJ1, DJ0, DJ1, z)                         \
  ACCX(W4, SI0, SI1, DI0, DI1, SJ0, SJ1, DJ0, DJ1, w)

  float4 Aw, Asi0, Asi1, Adi0, Adi1, Asj0, Asj1, Adj0, Adj1;
  float4 Bw, Bsi0, Bsi1, Bdi0, Bdi1, Bsj0, Bsj1, Bdj0, Bdj1;

  LOADG(Aw, Asi0, Asi1, Adi0, Adi1, Asj0, Asj1, Adj0, Adj1, 0)
  #pragma unroll
  for (int g = 0; g < 16; g += 2) {
    if (g + 1 < 16) {
      LOADG(Bw, Bsi0, Bsi1, Bdi0, Bdi1, Bsj0, Bsj1, Bdj0, Bdj1, (g + 1) * 4)
    }
    COMPG(Aw, Asi0, Asi1, Adi0, Adi1, Asj0, Asj1, Adj0, Adj1)
    if (g + 2 < 16) {
      LOADG(Aw, Asi0, Asi1, Adi0, Adi1, Asj0, Asj1, Adj0, Adj1, (g + 2) * 4)
    }
    COMPG(Bw, Bsi0, Bsi1, Bdi0, Bdi1, Bsj0, Bsj1, Bdj0, Bdj1)
  }
#undef COMPG
#undef ACCX
#undef LOADG

  const float b2f = b2[0];
  const double b2d = (double)b2f;

  #pragma unroll
  for (int a = 0; a < 2; ++a)
    #pragma unroll
    for (int c = 0; c < 2; ++c) {
      const int i = i0 + ty + 16 * a;
      const int j = j0 + tx + 16 * c;
      const float symf = 0.5f * (a1[a][c] + a2[a][c]) + b2f;
      const uint32_t m1 = (uint32_t)((b * NN + i) * NN + j);
      const uint32_t m2 = (uint32_t)((b * NN + j) * NN + i);

      float adj1, adj2;
      if (i == j) {
        adj1 = 0.f; adj2 = 0.f;
      } else {
        const float E = __expf(symf);
        const float L0a = -__logf(u_from_word(rand_word(2u * m1)));
        const float L1a = -__logf(u_from_word(rand_word(2u * m1 + 1u)));
        const float L0b = -__logf(u_from_word(rand_word(2u * m2)));
        const float L1b = -__logf(u_from_word(rand_word(2u * m2 + 1u)));
        const float pa = E * L1a, da = pa - L0a;
        const float pb = E * L1b, db = pb - L0b;
        const bool flagA = (fabsf(da) < 2e-3f * (pa + L0a)) || ((pa + L0a) < 2e-6f);
        const bool flagB = (fabsf(db) < 2e-3f * (pb + L0b)) || ((pb + L0b) < 2e-6f);
        adj1 = flagA ? decide_fallback(b, i, j, m1, b2d) : (da >= 0.f ? 1.f : 0.f);
        adj2 = flagB ? decide_fallback(b, i, j, m2, b2d) : (db >= 0.f ? 1.f : 0.f);
      }

      logits[m1] = symf;
      logits[m2] = symf;
      adj[m1] = adj1;
      adj[m2] = adj2;
    }
}

extern "C" void kernel_launch(void* const* d_in, const int* in_sizes, int n_in,
                              void* d_out, int out_size, void* d_ws, size_t ws_size,
                              hipStream_t stream) {
  const float* nf = (const float*)d_in[0];   // [4,1024,64]
  const float* W1 = (const float*)d_in[1];   // [128,64]
  const float* b1 = (const float*)d_in[2];   // [64]
  const float* W2 = (const float*)d_in[3];   // [64,1]
  const float* b2 = (const float*)d_in[4];   // [1]

  float* adj    = (float*)d_out;                       // [4,1024,1024]
  float* logits = adj + (size_t)NB * NN * NN;          // [4,1024,1024]

  stage1<<<dim3(512), dim3(256), 0, stream>>>(nf, W1, b1, W2);
  stage2<<<dim3(NB * 528), dim3(256), 0, stream>>>(b2, adj, logits);
}

// Round 12
// 157.755 us; speedup vs baseline: 4.6663x; 4.6663x over previous
//
#include <hip/hip_runtime.h>
#include <stdint.h>
#include <math.h>

#define NB 4
#define NN 1024
#define ND 64
#define RP 68   // padded f32 LDS row (multiple of 4 for b128 alignment)

// Static device scratch: f64 (exact fallback) + f32 (fast path) h arrays
__device__ double g_hs64[NB * NN * ND];
__device__ double g_hd64[NB * NN * ND];
__device__ float  g_hs32[NB * NN * ND];
__device__ float  g_hd32[NB * NN * ND];
__device__ double g_w2d[ND];
__device__ float  g_w2f[ND];

// ---- Threefry-2x32-20 core ----
__device__ __forceinline__ void threefry_core(uint32_t K0, uint32_t K1,
                                              uint32_t x0, uint32_t x1,
                                              uint32_t& o0, uint32_t& o1) {
  const uint32_t K2 = K0 ^ K1 ^ 0x1BD11BDAu;
  x0 += K0; x1 += K1;
#define TF_RND(r) { x0 += x1; x1 = (x1 << r) | (x1 >> (32 - r)); x1 ^= x0; }
  TF_RND(13) TF_RND(15) TF_RND(26) TF_RND(6)
  x0 += K1; x1 += K2 + 1u;
  TF_RND(17) TF_RND(29) TF_RND(16) TF_RND(24)
  x0 += K2; x1 += K0 + 2u;
  TF_RND(13) TF_RND(15) TF_RND(26) TF_RND(6)
  x0 += K0; x1 += K1 + 3u;
  TF_RND(17) TF_RND(29) TF_RND(16) TF_RND(24)
  x0 += K1; x1 += K2 + 4u;
  TF_RND(13) TF_RND(15) TF_RND(26) TF_RND(6)
  x0 += K2; x1 += K0 + 5u;
#undef TF_RND
  o0 = x0; o1 = x1;
}

// jax_threefry_partitionable stream (verified r3): word(L) = o0^o1, x=(0,L)
__device__ __forceinline__ uint32_t rand_word(uint32_t L) {
  uint32_t o0, o1;
  threefry_core(0u, 42u, 0u, L, o0, o1);
  return o0 ^ o1;
}

// exact f32 uniform(tiny,1) — bit-identical to JAX
__device__ __forceinline__ float u_from_word(uint32_t w) {
  uint32_t fb = (w >> 9) | 0x3f800000u;
  float f = __uint_as_float(fb) - 1.0f;
  const float tinyf = 1.17549435e-38f;
  return fmaxf(tinyf, f + tinyf);
}

// ---- exact-f64 fallback for near-boundary cells (matches r3/r4 pipeline) ----
__device__ __attribute__((noinline)) float decide_fallback(int b, int i, int j,
                                                           uint32_t m, double b2d) {
  const double* hsi = g_hs64 + ((size_t)(b * NN + i)) * ND;
  const double* hdi = g_hd64 + ((size_t)(b * NN + i)) * ND;
  const double* hsj = g_hs64 + ((size_t)(b * NN + j)) * ND;
  const double* hdj = g_hd64 + ((size_t)(b * NN + j)) * ND;
  double l1 = 0.0, l2 = 0.0;
  for (int d = 0; d < ND; ++d) {
    double w = g_w2d[d];
    l1 += fmax(hsi[d] + hdj[d], 0.0) * w;
    l2 += fmax(hsj[d] + hdi[d], 0.0) * w;
  }
  double sym = 0.5 * (l1 + l2) + b2d;
  double E = exp(sym);
  double L0 = -log((double)u_from_word(rand_word(2u * m)));
  double L1 = -log((double)u_from_word(rand_word(2u * m + 1u)));
  return (E * L1 >= L0) ? 1.0f : 0.0f;
}

// ---- Stage 1 (r11, fast): 512 blocks, 2 rows/thread-pair, float4 staging ----
__global__ __launch_bounds__(256) void stage1(const float* __restrict__ nf,
                                              const float* __restrict__ W1,
                                              const float* __restrict__ b1,
                                              const float* __restrict__ W2) {
  __shared__ float w1s[2 * ND][ND];   // 32 KB
  __shared__ float rows[8][ND];       // 2 KB
  const int tid = threadIdx.x;
  const float4* W14 = (const float4*)W1;
  float4* w1s4 = (float4*)w1s;
  #pragma unroll
  for (int p = 0; p < 8; ++p) w1s4[tid + 256 * p] = W14[tid + 256 * p];
  if (tid < 128) {     // 8 rows x 64 = 128 float4
    const int r = tid >> 4, c4 = (tid & 15) << 2;
    *(float4*)&rows[r][c4] =
        *(const float4*)(nf + ((size_t)blockIdx.x * 8 + r) * ND + c4);
  }
  __syncthreads();

  const int e = tid & 63;
  const int rg = tid >> 6;            // 0..3 -> rows rg*2, rg*2+1
  const int r0 = rg * 2, r1 = rg * 2 + 1;

  double as0 = 0.0, as1 = 0.0, ad0 = 0.0, ad1 = 0.0;
  #pragma unroll 4
  for (int k = 0; k < ND; ++k) {
    const double ws = (double)w1s[k][e];
    const double wd = (double)w1s[ND + k][e];
    const double x0 = (double)rows[r0][k];
    const double x1 = (double)rows[r1][k];
    as0 = fma(x0, ws, as0);  as1 = fma(x1, ws, as1);
    ad0 = fma(x0, wd, ad0);  ad1 = fma(x1, wd, ad1);
  }
  const double b1e = (double)b1[e];
  ad0 += b1e;  ad1 += b1e;

  const size_t bn0 = (size_t)blockIdx.x * 8 + r0;
  const size_t bn1 = bn0 + 1;
  g_hs64[bn0 * ND + e] = as0;  g_hs64[bn1 * ND + e] = as1;
  g_hd64[bn0 * ND + e] = ad0;  g_hd64[bn1 * ND + e] = ad1;
  g_hs32[bn0 * ND + e] = (float)as0;  g_hs32[bn1 * ND + e] = (float)as1;
  g_hd32[bn0 * ND + e] = (float)ad0;  g_hd32[bn1 * ND + e] = (float)ad1;

  if (blockIdx.x == 0 && tid < ND) {
    g_w2d[tid] = (double)W2[tid];
    g_w2f[tid] = W2[tid];
  }
}

// ---- Stage 2 (r6, best measured): f32 32x32 pair tile, 2x2/thread ----
__global__ __launch_bounds__(256, 4) void stage2(const float* __restrict__ b2,
                                                 float* __restrict__ adj,
                                                 float* __restrict__ logits) {
  const int t = blockIdx.x;
  const int b = t / 528;
  const int k = t - b * 528;
#define TRI_S(x) ((x) * 32 - ((x) * ((x) - 1)) / 2)
  int bi = (int)((65.0 - sqrt((double)(4225 - 8 * k))) * 0.5);
  while (k >= TRI_S(bi + 1)) ++bi;
  while (k < TRI_S(bi)) --bi;
  const int bj = bi + (k - TRI_S(bi));
#undef TRI_S
  const int i0 = bi * 32, j0 = bj * 32;

  __shared__ float sh_si[32][RP], sh_di[32][RP];
  __shared__ float sh_sj[32][RP], sh_dj[32][RP];
  __shared__ float w2s[ND];

  const int tid = threadIdx.x;
  {
    const float4* src_si = (const float4*)(g_hs32 + ((size_t)(b * NN + i0)) * ND);
    const float4* src_di = (const float4*)(g_hd32 + ((size_t)(b * NN + i0)) * ND);
    const float4* src_sj = (const float4*)(g_hs32 + ((size_t)(b * NN + j0)) * ND);
    const float4* src_dj = (const float4*)(g_hd32 + ((size_t)(b * NN + j0)) * ND);
    #pragma unroll
    for (int p = 0; p < 2; ++p) {
      const int q = tid + 256 * p;          // float4 index, 0..511
      const int r = q >> 4, c4 = (q & 15) << 2;
      *(float4*)&sh_si[r][c4] = src_si[q];
      *(float4*)&sh_di[r][c4] = src_di[q];
      *(float4*)&sh_sj[r][c4] = src_sj[q];
      *(float4*)&sh_dj[r][c4] = src_dj[q];
    }
    if (tid < ND) w2s[tid] = g_w2f[tid];
  }
  __syncthreads();

  const int tx = tid & 15, ty = tid >> 4;

  float a1[2][2] = {{0.f, 0.f}, {0.f, 0.f}};
  float a2[2][2] = {{0.f, 0.f}, {0.f, 0.f}};

  #pragma unroll 4
  for (int d = 0; d < ND; d += 4) {
    float wv[4], si[2][4], di[2][4], sj[2][4], dj[2][4];
    *(float4*)wv    = *(const float4*)&w2s[d];
    *(float4*)si[0] = *(const float4*)&sh_si[ty][d];
    *(float4*)si[1] = *(const float4*)&sh_si[ty + 16][d];
    *(float4*)di[0] = *(const float4*)&sh_di[ty][d];
    *(float4*)di[1] = *(const float4*)&sh_di[ty + 16][d];
    *(float4*)sj[0] = *(const float4*)&sh_sj[tx][d];
    *(float4*)sj[1] = *(const float4*)&sh_sj[tx + 16][d];
    *(float4*)dj[0] = *(const float4*)&sh_dj[tx][d];
    *(float4*)dj[1] = *(const float4*)&sh_dj[tx + 16][d];
    #pragma unroll
    for (int dd = 0; dd < 4; ++dd) {
      const float w = wv[dd];
      #pragma unroll
      for (int a = 0; a < 2; ++a)
        #pragma unroll
        for (int c = 0; c < 2; ++c) {
          a1[a][c] = fmaf(fmaxf(si[a][dd] + dj[c][dd], 0.f), w, a1[a][c]);
          a2[a][c] = fmaf(fmaxf(sj[c][dd] + di[a][dd], 0.f), w, a2[a][c]);
        }
    }
  }

  const float b2f = b2[0];
  const double b2d = (double)b2f;

  #pragma unroll
  for (int a = 0; a < 2; ++a)
    #pragma unroll
    for (int c = 0; c < 2; ++c) {
      const int i = i0 + ty + 16 * a;
      const int j = j0 + tx + 16 * c;
      const float symf = 0.5f * (a1[a][c] + a2[a][c]) + b2f;
      const uint32_t m1 = (uint32_t)((b * NN + i) * NN + j);
      const uint32_t m2 = (uint32_t)((b * NN + j) * NN + i);

      const float E = __expf(symf);
      const float L0a = -__logf(u_from_word(rand_word(2u * m1)));
      const float L1a = -__logf(u_from_word(rand_word(2u * m1 + 1u)));
      const float L0b = -__logf(u_from_word(rand_word(2u * m2)));
      const float L1b = -__logf(u_from_word(rand_word(2u * m2 + 1u)));

      float adj1, adj2;
      if (i == j) {
        adj1 = 0.f; adj2 = 0.f;
      } else {
        const float pa = E * L1a, da = pa - L0a;
        const float pb = E * L1b, db = pb - L0b;
        const bool flagA = (fabsf(da) < 2e-3f * (pa + L0a)) || ((pa + L0a) < 2e-6f);
        const bool flagB = (fabsf(db) < 2e-3f * (pb + L0b)) || ((pb + L0b) < 2e-6f);
        adj1 = flagA ? decide_fallback(b, i, j, m1, b2d) : (da >= 0.f ? 1.f : 0.f);
        adj2 = flagB ? decide_fallback(b, i, j, m2, b2d) : (db >= 0.f ? 1.f : 0.f);
      }

      logits[m1] = symf;
      logits[m2] = symf;
      adj[m1] = adj1;
      adj[m2] = adj2;
    }
}

extern "C" void kernel_launch(void* const* d_in, const int* in_sizes, int n_in,
                              void* d_out, int out_size, void* d_ws, size_t ws_size,
                              hipStream_t stream) {
  const float* nf = (const float*)d_in[0];   // [4,1024,64]
  const float* W1 = (const float*)d_in[1];   // [128,64]
  const float* b1 = (const float*)d_in[2];   // [64]
  const float* W2 = (const float*)d_in[3];   // [64,1]
  const float* b2 = (const float*)d_in[4];   // [1]

  float* adj    = (float*)d_out;                       // [4,1024,1024]
  float* logits = adj + (size_t)NB * NN * NN;          // [4,1024,1024]

  stage1<<<dim3(512), dim3(256), 0, stream>>>(nf, W1, b1, W2);
  stage2<<<dim3(NB * 528), dim3(256), 0, stream>>>(b2, adj, logits);
}